// Round 2
// baseline (2906.292 us; speedup 1.0000x reference)
//
#include <hip/hip_runtime.h>
#include <hip/hip_bf16.h>
#include <cstdint>

#define TPB 256

typedef __attribute__((ext_vector_type(8))) short short8v;
typedef __attribute__((ext_vector_type(4))) float float4v;

__device__ inline ushort f2bf(float f) {
  union { float f; uint u; } c; c.f = f;
  uint b = c.u;
  uint r = (b + 0x7fffu + ((b >> 16) & 1u)) >> 16;
  return (ushort)r;
}

// ---------------- init ----------------
__global__ __launch_bounds__(TPB) void k_init(int* deg_td, int* deg_bu,
    float* pool_td, float* pool_bu, int* first, float* cnt, int N, int GH, int G) {
  int i = blockIdx.x * TPB + threadIdx.x;
  if (i < N) { deg_td[i] = 1; deg_bu[i] = 1; }
  if (i < GH) { pool_td[i] = 0.f; pool_bu[i] = 0.f; }
  if (i < G) { first[i] = 0x7fffffff; cnt[i] = 0.f; }
}

// ---------------- stats: LDS histogram, few global atomics ----------------
__global__ __launch_bounds__(TPB) void k_stats(const int* __restrict__ batch,
    int* first, float* cnt, int N, int G) {
  __shared__ int h[1024];
  __shared__ int fm[1024];
  if (G <= 1024) {
    for (int t = threadIdx.x; t < G; t += TPB) { h[t] = 0; fm[t] = 0x7fffffff; }
    __syncthreads();
    int i = blockIdx.x * TPB + threadIdx.x;
    if (i < N) { int g = batch[i]; atomicAdd(&h[g], 1); atomicMin(&fm[g], i); }
    __syncthreads();
    for (int t = threadIdx.x; t < G; t += TPB) {
      if (h[t]) { atomicAdd(&cnt[t], (float)h[t]); atomicMin(&first[t], fm[t]); }
    }
  } else {
    int i = blockIdx.x * TPB + threadIdx.x;
    if (i < N) { int g = batch[i]; atomicMin(&first[g], i); atomicAdd(&cnt[g], 1.f); }
  }
}

__global__ __launch_bounds__(TPB) void k_deg(const int* __restrict__ s,
    const int* __restrict__ d, int* deg_td, int* deg_bu, int E) {
  int e = blockIdx.x * TPB + threadIdx.x;
  if (e < E) { atomicAdd(&deg_td[d[e]], 1); atomicAdd(&deg_bu[s[e]], 1); }
}

__global__ __launch_bounds__(TPB) void k_dinv(const int* __restrict__ deg_td,
    const int* __restrict__ deg_bu, float* dinv_td, float* dinv_bu, int N) {
  int i = blockIdx.x * TPB + threadIdx.x;
  if (i < N) {
    dinv_td[i] = rsqrtf((float)deg_td[i]);
    dinv_bu[i] = rsqrtf((float)deg_bu[i]);
  }
}

// ---------------- root projection: R = relu(x[root]) @ W2[H:H+F, :] (f32, tiny) ----------------
__global__ __launch_bounds__(64) void k_root(const float* __restrict__ x,
    const int* __restrict__ first, const float* __restrict__ W2_td,
    const float* __restrict__ W2_bu, float* R_td, float* R_bu, int F, int H) {
  __shared__ float xr[256];
  int g = blockIdx.x;
  int c = blockIdx.y * 64 + threadIdx.x;
  int root = first[g];
  for (int k = threadIdx.x; k < F; k += 64) xr[k] = fmaxf(x[(size_t)root * F + k], 0.f);
  __syncthreads();
  float atd = 0.f, abu = 0.f;
  for (int k = 0; k < F; ++k) {
    float v = xr[k];
    atd += v * W2_td[(size_t)(H + k) * H + c];
    abu += v * W2_bu[(size_t)(H + k) * H + c];
  }
  R_td[(size_t)g * H + c] = atd;
  R_bu[(size_t)g * H + c] = abu;
}

// ---------------- cast f32 -> bf16 (optional relu), 8 elems/thread ----------------
__global__ __launch_bounds__(TPB) void k_cast(const float* __restrict__ in,
    ushort* __restrict__ out, size_t n8, int relu) {
  size_t i = (size_t)blockIdx.x * TPB + threadIdx.x;
  if (i >= n8) return;
  const float4* p = (const float4*)in + i * 2;
  float4 v0 = p[0], v1 = p[1];
  if (relu) {
    v0.x = fmaxf(v0.x, 0.f); v0.y = fmaxf(v0.y, 0.f);
    v0.z = fmaxf(v0.z, 0.f); v0.w = fmaxf(v0.w, 0.f);
    v1.x = fmaxf(v1.x, 0.f); v1.y = fmaxf(v1.y, 0.f);
    v1.z = fmaxf(v1.z, 0.f); v1.w = fmaxf(v1.w, 0.f);
  }
  ushort u[8];
  u[0] = f2bf(v0.x); u[1] = f2bf(v0.y); u[2] = f2bf(v0.z); u[3] = f2bf(v0.w);
  u[4] = f2bf(v1.x); u[5] = f2bf(v1.y); u[6] = f2bf(v1.z); u[7] = f2bf(v1.w);
  *(uint4*)(out + i * 8) = *(const uint4*)u;
}

// ---------------- transpose-cast weight: Wt[n][k] = bf16(W[(r0+k)*ldn + n]) ----------------
__global__ __launch_bounds__(TPB) void k_prep_w(const float* __restrict__ W,
    ushort* __restrict__ Wt, int K, int Nn, int r0) {
  int idx = blockIdx.x * TPB + threadIdx.x;
  if (idx >= K * Nn) return;
  int k = idx / Nn;
  int n = idx - k * Nn;
  Wt[(size_t)n * K + k] = f2bf(W[(size_t)(r0 + k) * Nn + n]);
}

// ---------------- bf16 MFMA GEMM: C[M][N] = A[M][K] @ Bt[N][K]^T (+ Rb[batch[m]]) ----------------
// LDS-free: K=256, Bt (128KB) is L2-resident. Wave = 16 rows x full N.
// Frag layouts (guide-verified): A/B lane l: 16-idx = l&15, k = (l>>4)*8 + e.
//                                C/D lane l: col = l&15, row = (l>>4)*4 + reg.
#define NT16 16  // N/16 == 16 (N==256)
__global__ __launch_bounds__(TPB) void gemm_mfma(
    const ushort* __restrict__ A, const ushort* __restrict__ Bt,
    float* __restrict__ C, const float* __restrict__ Rb,
    const int* __restrict__ batch, int M, int K, int N) {
  const int wid = threadIdx.x >> 6;
  const int lane = threadIdx.x & 63;
  const int m0 = (blockIdx.x * 4 + wid) * 16;
  const int lr = lane & 15;
  const int lk = (lane >> 4) * 8;
  float4v acc[NT16];
#pragma unroll
  for (int t = 0; t < NT16; ++t) acc[t] = (float4v)0.f;
  const ushort* arow = &A[(size_t)(m0 + lr) * K + lk];
  for (int kk = 0; kk < K; kk += 32) {
    short8v a = *(const short8v*)&arow[kk];
#pragma unroll
    for (int t = 0; t < NT16; ++t) {
      short8v b = *(const short8v*)&Bt[(size_t)(t * 16 + lr) * K + kk + lk];
      acc[t] = __builtin_amdgcn_mfma_f32_16x16x32_bf16(a, b, acc[t], 0, 0, 0);
    }
  }
  const int rbase = m0 + (lane >> 4) * 4;
#pragma unroll
  for (int r = 0; r < 4; ++r) {
    int row = rbase + r;
    const float* rb = Rb ? &Rb[(size_t)batch[row] * N] : (const float*)nullptr;
#pragma unroll
    for (int t = 0; t < NT16; ++t) {
      int col = t * 16 + lr;
      float v = acc[t][r];
      if (rb) v += rb[col];
      C[(size_t)row * N + col] = v;
    }
  }
}

// ---------------- conv: self-loop init  y = xw*dinv^2 + bias ----------------
__global__ __launch_bounds__(TPB) void k_conv_init(const float* __restrict__ xw,
    float* __restrict__ y, const float* __restrict__ dinv,
    const float* __restrict__ bias, int N, int H) {
  int idx = blockIdx.x * TPB + threadIdx.x;
  int tot = N * (H >> 2);
  if (idx >= tot) return;
  int i = idx / (H >> 2);
  int c4 = (idx - i * (H >> 2)) << 2;
  float di = dinv[i];
  float s = di * di;
  float4 v = *(const float4*)&xw[(size_t)i * H + c4];
  float4 b = *(const float4*)&bias[c4];
  float4 o;
  o.x = v.x * s + b.x; o.y = v.y * s + b.y; o.z = v.z * s + b.z; o.w = v.w * s + b.w;
  *(float4*)&y[(size_t)i * H + c4] = o;
}

// ---------------- conv: edge scatter, 4 edges/block, float4 reads ----------------
__global__ __launch_bounds__(TPB) void k_conv_edges(const float* __restrict__ xw,
    float* __restrict__ y, const int* __restrict__ s, const int* __restrict__ d,
    const float* __restrict__ dinv, int E, int H) {
  int e = blockIdx.x * 4 + (threadIdx.x >> 6);
  if (e >= E) return;
  int lane = threadIdx.x & 63;
  int si = s[e], di = d[e];
  float nrm = dinv[si] * dinv[di];
  float4 v = *(const float4*)&xw[(size_t)si * H + lane * 4];
  size_t yb = (size_t)di * H + lane * 4;
  atomicAdd(&y[yb + 0], v.x * nrm);
  atomicAdd(&y[yb + 1], v.y * nrm);
  atomicAdd(&y[yb + 2], v.z * nrm);
  atomicAdd(&y[yb + 3], v.w * nrm);
}

// ---------------- pool: pool[g] += relu(y[i]), batched flush ----------------
__global__ __launch_bounds__(TPB) void k_pool(const float* __restrict__ y,
    float* __restrict__ pool, const int* __restrict__ batch, int N, int H) {
  int c = threadIdx.x;  // H == 256
  int n0 = blockIdx.x * 256;
  int n1 = min(n0 + 256, N);
  float acc = 0.f;
  int cur = batch[n0];
  for (int i = n0; i < n1; ++i) {
    int g = batch[i];
    if (g != cur) { atomicAdd(&pool[(size_t)cur * H + c], acc); acc = 0.f; cur = g; }
    acc += fmaxf(y[(size_t)i * H + c], 0.f);
  }
  atomicAdd(&pool[(size_t)cur * H + c], acc);
}

// ---------------- head ----------------
__global__ __launch_bounds__(128) void k_head(const float* __restrict__ pool_td,
    const float* __restrict__ pool_bu, const float* __restrict__ cnt,
    const float* __restrict__ Wl, const float* __restrict__ bl,
    float* __restrict__ out, int H, int C) {
  int g = blockIdx.x;
  int t = threadIdx.x;
  float inv = 1.f / cnt[g];
  float acc[8];
  for (int c = 0; c < C; ++c) acc[c] = 0.f;
  int twoH = 2 * H;
  for (int d0 = t; d0 < twoH; d0 += 128) {
    float v = (d0 < H ? pool_td[(size_t)g * H + d0] : pool_bu[(size_t)g * H + d0 - H]) * inv;
    for (int c = 0; c < C; ++c) acc[c] += v * Wl[(size_t)d0 * C + c];
  }
  __shared__ float red[128 * 8];
  for (int c = 0; c < C; ++c) red[t * C + c] = acc[c];
  __syncthreads();
  for (int off = 64; off > 0; off >>= 1) {
    if (t < off)
      for (int c = 0; c < C; ++c) red[t * C + c] += red[(t + off) * C + c];
    __syncthreads();
  }
  if (t == 0) {
    float l[8];
    float m = -1e30f;
    for (int c = 0; c < C; ++c) { l[c] = red[c] + bl[c]; m = fmaxf(m, l[c]); }
    float ssum = 0.f;
    for (int c = 0; c < C; ++c) ssum += expf(l[c] - m);
    float ls = logf(ssum);
    for (int c = 0; c < C; ++c) out[(size_t)g * C + c] = l[c] - m - ls;
  }
}

extern "C" void kernel_launch(void* const* d_in, const int* in_sizes, int n_in,
                              void* d_out, int out_size, void* d_ws, size_t ws_size,
                              hipStream_t stream) {
  const float* x     = (const float*)d_in[0];
  const int*   ei    = (const int*)d_in[1];
  const int*   batch = (const int*)d_in[2];
  const float* W1_td = (const float*)d_in[4];
  const float* b1_td = (const float*)d_in[5];
  const float* W1_bu = (const float*)d_in[6];
  const float* b1_bu = (const float*)d_in[7];
  const float* W2_td = (const float*)d_in[8];
  const float* b2_td = (const float*)d_in[9];
  const float* W2_bu = (const float*)d_in[10];
  const float* b2_bu = (const float*)d_in[11];
  const float* Wl    = (const float*)d_in[12];
  const float* bl    = (const float*)d_in[13];
  float* out = (float*)d_out;

  const int N = in_sizes[2];
  const int H = in_sizes[5];
  const int F = in_sizes[0] / N;
  const int E = in_sizes[1] / 2;
  const int C = in_sizes[13];
  const int G = out_size / C;

  const int* srcp = ei;
  const int* dstp = ei + E;

  const size_t NH = (size_t)N * H;
  const size_t NF = (size_t)N * F;
  const size_t KH = (size_t)F * H;  // weight elements (K==H==256 here)

  ushort* x_bf   = (ushort*)d_ws;                 // N*F bf16
  ushort* ab     = x_bf + NF;                     // N*H bf16
  ushort* Wt1_td = ab + NH;                       // H*F
  ushort* Wt1_bu = Wt1_td + KH;
  ushort* Wt2_td = Wt1_bu + KH;
  ushort* Wt2_bu = Wt2_td + KH;
  float* P       = (float*)(Wt2_bu + KH);         // N*H f32
  float* Q       = P + NH;                        // N*H f32
  float* dinv_td = Q + NH;                        // N
  float* dinv_bu = dinv_td + N;                   // N
  float* R_td    = dinv_bu + N;                   // G*H
  float* R_bu    = R_td + (size_t)G * H;
  float* pool_td = R_bu + (size_t)G * H;
  float* pool_bu = pool_td + (size_t)G * H;
  float* cnt     = pool_bu + (size_t)G * H;       // G
  int* deg_td    = (int*)(cnt + G);               // N
  int* deg_bu    = deg_td + N;                    // N
  int* first     = deg_bu + N;                    // G
  size_t need = (size_t)((char*)(first + G) - (char*)d_ws);
  if (need > ws_size) return;

  const int nbN = (N + TPB - 1) / TPB;
  const int nbE = (E + TPB - 1) / TPB;
  const int GH = G * H;
  const int nbNH4 = (int)((NH / 4 + TPB - 1) / TPB);
  const int nbNH8 = (int)((NH / 8 + TPB - 1) / TPB);
  const int nbKH = (int)((KH + TPB - 1) / TPB);
  const int nbEdge = (E + 3) / 4;
  const dim3 gemmGrid(N / 64);

  k_init<<<nbN, TPB, 0, stream>>>(deg_td, deg_bu, pool_td, pool_bu, first, cnt, N, GH, G);
  k_stats<<<nbN, TPB, 0, stream>>>(batch, first, cnt, N, G);
  k_deg<<<nbE, TPB, 0, stream>>>(srcp, dstp, deg_td, deg_bu, E);
  k_dinv<<<nbN, TPB, 0, stream>>>(deg_td, deg_bu, dinv_td, dinv_bu, N);
  k_root<<<dim3(G, H / 64), 64, 0, stream>>>(x, first, W2_td, W2_bu, R_td, R_bu, F, H);

  k_prep_w<<<nbKH, TPB, 0, stream>>>(W1_td, Wt1_td, F, H, 0);
  k_prep_w<<<nbKH, TPB, 0, stream>>>(W1_bu, Wt1_bu, F, H, 0);
  k_prep_w<<<nbKH, TPB, 0, stream>>>(W2_td, Wt2_td, H, H, 0);
  k_prep_w<<<nbKH, TPB, 0, stream>>>(W2_bu, Wt2_bu, H, H, 0);
  k_cast<<<nbNH8, TPB, 0, stream>>>(x, x_bf, NF / 8, 0);

  // ---- td chain ----
  gemm_mfma<<<gemmGrid, TPB, 0, stream>>>(x_bf, Wt1_td, P, nullptr, batch, N, F, H);
  k_conv_init<<<nbNH4, TPB, 0, stream>>>(P, Q, dinv_td, b1_td, N, H);
  k_conv_edges<<<nbEdge, TPB, 0, stream>>>(P, Q, srcp, dstp, dinv_td, E, H);
  k_cast<<<nbNH8, TPB, 0, stream>>>(Q, ab, NH / 8, 1);
  gemm_mfma<<<gemmGrid, TPB, 0, stream>>>(ab, Wt2_td, P, R_td, batch, N, H, H);
  k_conv_init<<<nbNH4, TPB, 0, stream>>>(P, Q, dinv_td, b2_td, N, H);
  k_conv_edges<<<nbEdge, TPB, 0, stream>>>(P, Q, srcp, dstp, dinv_td, E, H);
  k_pool<<<(N + 255) / 256, TPB, 0, stream>>>(Q, pool_td, batch, N, H);

  // ---- bu chain ----
  gemm_mfma<<<gemmGrid, TPB, 0, stream>>>(x_bf, Wt1_bu, P, nullptr, batch, N, F, H);
  k_conv_init<<<nbNH4, TPB, 0, stream>>>(P, Q, dinv_bu, b1_bu, N, H);
  k_conv_edges<<<nbEdge, TPB, 0, stream>>>(P, Q, dstp, srcp, dinv_bu, E, H);
  k_cast<<<nbNH8, TPB, 0, stream>>>(Q, ab, NH / 8, 1);
  gemm_mfma<<<gemmGrid, TPB, 0, stream>>>(ab, Wt2_bu, P, R_bu, batch, N, H, H);
  k_conv_init<<<nbNH4, TPB, 0, stream>>>(P, Q, dinv_bu, b2_bu, N, H);
  k_conv_edges<<<nbEdge, TPB, 0, stream>>>(P, Q, dstp, srcp, dinv_bu, E, H);
  k_pool<<<(N + 255) / 256, TPB, 0, stream>>>(Q, pool_bu, batch, N, H);

  k_head<<<G, 128, 0, stream>>>(pool_td, pool_bu, cnt, Wl, bl, out, H, C);
}

// Round 3
// 814.180 us; speedup vs baseline: 3.5696x; 3.5696x over previous
//
#include <hip/hip_runtime.h>
#include <hip/hip_bf16.h>
#include <cstdint>

#define TPB 256

typedef __attribute__((ext_vector_type(8))) short short8v;
typedef __attribute__((ext_vector_type(4))) float float4v;

__device__ inline ushort f2bf(float f) {
  union { float f; uint u; } c; c.f = f;
  uint b = c.u;
  return (ushort)((b + 0x7fffu + ((b >> 16) & 1u)) >> 16);
}
__device__ inline float bf2f(ushort u) {
  union { uint u; float f; } c; c.u = ((uint)u) << 16;
  return c.f;
}

// ---------------- init ----------------
__global__ __launch_bounds__(TPB) void k_init(int* deg_td, int* deg_bu, int* parent,
    float* pool_td, float* pool_bu, int* first, float* cnt, int N, int GH, int G) {
  int i = blockIdx.x * TPB + threadIdx.x;
  if (i < N) { deg_td[i] = 1; deg_bu[i] = 1; parent[i] = -1; }
  if (i < GH) { pool_td[i] = 0.f; pool_bu[i] = 0.f; }
  if (i < G) { first[i] = 0x7fffffff; cnt[i] = 0.f; }
}

// ---------------- stats: LDS histogram ----------------
__global__ __launch_bounds__(TPB) void k_stats(const int* __restrict__ batch,
    int* first, float* cnt, int N, int G) {
  __shared__ int h[1024];
  __shared__ int fm[1024];
  if (G <= 1024) {
    for (int t = threadIdx.x; t < G; t += TPB) { h[t] = 0; fm[t] = 0x7fffffff; }
    __syncthreads();
    int i = blockIdx.x * TPB + threadIdx.x;
    if (i < N) { int g = batch[i]; atomicAdd(&h[g], 1); atomicMin(&fm[g], i); }
    __syncthreads();
    for (int t = threadIdx.x; t < G; t += TPB) {
      if (h[t]) { atomicAdd(&cnt[t], (float)h[t]); atomicMin(&first[t], fm[t]); }
    }
  } else {
    int i = blockIdx.x * TPB + threadIdx.x;
    if (i < N) { int g = batch[i]; atomicMin(&first[g], i); atomicAdd(&cnt[g], 1.f); }
  }
}

__global__ __launch_bounds__(TPB) void k_deg(const int* __restrict__ s,
    const int* __restrict__ d, int* deg_td, int* deg_bu, int* parent, int E) {
  int e = blockIdx.x * TPB + threadIdx.x;
  if (e < E) {
    atomicAdd(&deg_td[d[e]], 1);
    atomicAdd(&deg_bu[s[e]], 1);
    parent[d[e]] = s[e];  // dst unique (tree) -> race-free
  }
}

__global__ __launch_bounds__(TPB) void k_dinv(const int* __restrict__ deg_td,
    const int* __restrict__ deg_bu, float* dinv_td, float* dinv_bu, int N) {
  int i = blockIdx.x * TPB + threadIdx.x;
  if (i < N) {
    dinv_td[i] = rsqrtf((float)deg_td[i]);
    dinv_bu[i] = rsqrtf((float)deg_bu[i]);
  }
}

// ---------------- CSR build: scan of (deg_bu - 1) ----------------
__global__ __launch_bounds__(TPB) void k_scan1(const int* __restrict__ deg,
    int* bsum, int N) {
  __shared__ int s[TPB];
  int i = blockIdx.x * TPB + threadIdx.x;
  s[threadIdx.x] = (i < N) ? deg[i] - 1 : 0;
  __syncthreads();
  for (int off = TPB / 2; off > 0; off >>= 1) {
    if (threadIdx.x < off) s[threadIdx.x] += s[threadIdx.x + off];
    __syncthreads();
  }
  if (threadIdx.x == 0) bsum[blockIdx.x] = s[0];
}

__global__ __launch_bounds__(1024) void k_scan2(int* bsum, int NB) {
  __shared__ int s[1024];
  int t = threadIdx.x;
  int own = (t < NB) ? bsum[t] : 0;
  s[t] = own;
  __syncthreads();
  for (int off = 1; off < 1024; off <<= 1) {
    int v = (t >= off) ? s[t - off] : 0;
    __syncthreads();
    s[t] += v;
    __syncthreads();
  }
  if (t < NB) bsum[t] = s[t] - own;  // exclusive
}

__global__ __launch_bounds__(TPB) void k_scan3(const int* __restrict__ deg,
    const int* __restrict__ bsum, int* offs, int* cursor, int N) {
  __shared__ int s[TPB];
  int t = threadIdx.x;
  int i = blockIdx.x * TPB + t;
  int v = (i < N) ? deg[i] - 1 : 0;
  s[t] = v;
  __syncthreads();
  for (int off = 1; off < TPB; off <<= 1) {
    int u = (t >= off) ? s[t - off] : 0;
    __syncthreads();
    s[t] += u;
    __syncthreads();
  }
  int excl = bsum[blockIdx.x] + s[t] - v;
  if (i < N) {
    offs[i] = excl;
    cursor[i] = excl;
    if (i == N - 1) offs[N] = excl + v;
  }
}

__global__ __launch_bounds__(TPB) void k_fill(const int* __restrict__ s,
    const int* __restrict__ d, int* cursor, int* childs, int E) {
  int e = blockIdx.x * TPB + threadIdx.x;
  if (e < E) {
    int pos = atomicAdd(&cursor[s[e]], 1);
    childs[pos] = d[e];
  }
}

// ---------------- root projection (f32, tiny) ----------------
__global__ __launch_bounds__(64) void k_root(const float* __restrict__ x,
    const int* __restrict__ first, const float* __restrict__ W2_td,
    const float* __restrict__ W2_bu, float* R_td, float* R_bu, int F, int H) {
  __shared__ float xr[256];
  int g = blockIdx.x;
  int c = blockIdx.y * 64 + threadIdx.x;
  int root = first[g];
  for (int k = threadIdx.x; k < F; k += 64) xr[k] = fmaxf(x[(size_t)root * F + k], 0.f);
  __syncthreads();
  float atd = 0.f, abu = 0.f;
  for (int k = 0; k < F; ++k) {
    float v = xr[k];
    atd += v * W2_td[(size_t)(H + k) * H + c];
    abu += v * W2_bu[(size_t)(H + k) * H + c];
  }
  R_td[(size_t)g * H + c] = atd;
  R_bu[(size_t)g * H + c] = abu;
}

// ---------------- cast f32 -> bf16 ----------------
__global__ __launch_bounds__(TPB) void k_cast(const float* __restrict__ in,
    ushort* __restrict__ out, size_t n8) {
  size_t i = (size_t)blockIdx.x * TPB + threadIdx.x;
  if (i >= n8) return;
  const float4* p = (const float4*)in + i * 2;
  float4 v0 = p[0], v1 = p[1];
  ushort u[8];
  u[0] = f2bf(v0.x); u[1] = f2bf(v0.y); u[2] = f2bf(v0.z); u[3] = f2bf(v0.w);
  u[4] = f2bf(v1.x); u[5] = f2bf(v1.y); u[6] = f2bf(v1.z); u[7] = f2bf(v1.w);
  *(uint4*)(out + i * 8) = *(const uint4*)u;
}

// ---------------- transpose-cast weight ----------------
__global__ __launch_bounds__(TPB) void k_prep_w(const float* __restrict__ W,
    ushort* __restrict__ Wt, int K, int Nn) {
  int idx = blockIdx.x * TPB + threadIdx.x;
  if (idx >= K * Nn) return;
  int k = idx / Nn;
  int n = idx - k * Nn;
  Wt[(size_t)n * K + k] = f2bf(W[(size_t)k * Nn + n]);
}

// ---------------- bf16 MFMA GEMM: 32 rows/wave, bf16 out, optional +R[batch] ----------------
#define NT16 16  // N == 256
__global__ __launch_bounds__(TPB) void gemm_mfma(
    const ushort* __restrict__ A, const ushort* __restrict__ Bt,
    ushort* __restrict__ Cbf, const float* __restrict__ Rb,
    const int* __restrict__ batch, int M, int K, int N) {
  const int wave = (blockIdx.x * TPB + threadIdx.x) >> 6;
  const int lane = threadIdx.x & 63;
  const int m0 = wave * 32;
  if (m0 >= M) return;
  const int lr = lane & 15;
  const int lk = (lane >> 4) * 8;
  float4v acc[2][NT16];
#pragma unroll
  for (int h = 0; h < 2; ++h)
#pragma unroll
    for (int t = 0; t < NT16; ++t) acc[h][t] = (float4v)0.f;
  const ushort* a0p = &A[(size_t)(m0 + lr) * K + lk];
  const ushort* a1p = &A[(size_t)(m0 + 16 + lr) * K + lk];
  for (int kk = 0; kk < K; kk += 32) {
    short8v a0 = *(const short8v*)&a0p[kk];
    short8v a1 = *(const short8v*)&a1p[kk];
#pragma unroll
    for (int t = 0; t < NT16; ++t) {
      short8v b = *(const short8v*)&Bt[(size_t)(t * 16 + lr) * K + kk + lk];
      acc[0][t] = __builtin_amdgcn_mfma_f32_16x16x32_bf16(a0, b, acc[0][t], 0, 0, 0);
      acc[1][t] = __builtin_amdgcn_mfma_f32_16x16x32_bf16(a1, b, acc[1][t], 0, 0, 0);
    }
  }
#pragma unroll
  for (int h = 0; h < 2; ++h) {
    const int rbase = m0 + h * 16 + (lane >> 4) * 4;
#pragma unroll
    for (int r = 0; r < 4; ++r) {
      int row = rbase + r;
      const float* rb = Rb ? &Rb[(size_t)batch[row] * N] : (const float*)nullptr;
#pragma unroll
      for (int t = 0; t < NT16; ++t) {
        int col = t * 16 + lr;
        float v = acc[h][t][r];
        if (rb) v += rb[col];
        Cbf[(size_t)row * N + col] = f2bf(v);
      }
    }
  }
}

// ---------------- conv gather core: y[0..3] for (node, lane) ----------------
// CSR=false: neighbor = parent[node]. CSR=true: neighbors = childs[offs[i]..offs[i+1])
template <bool CSR>
__device__ inline void conv_row(int node, int lane, const ushort* __restrict__ xw,
    const int* __restrict__ parent, const int* __restrict__ offs,
    const int* __restrict__ childs, const float* __restrict__ dinv,
    const float* __restrict__ bias, int H, float y[4]) {
  const int c4 = lane * 4;
  float di = dinv[node];
  ushort4 v = *(const ushort4*)(xw + (size_t)node * H + c4);
  float a0 = bf2f(v.x) * di, a1 = bf2f(v.y) * di, a2 = bf2f(v.z) * di, a3 = bf2f(v.w) * di;
  if (CSR) {
    int k0 = offs[node], k1 = offs[node + 1];
    for (int k = k0; k < k1; ++k) {
      int c = childs[k];
      float dc = dinv[c];
      ushort4 u = *(const ushort4*)(xw + (size_t)c * H + c4);
      a0 += bf2f(u.x) * dc; a1 += bf2f(u.y) * dc;
      a2 += bf2f(u.z) * dc; a3 += bf2f(u.w) * dc;
    }
  } else {
    int p = parent[node];
    if (p >= 0) {
      float dp = dinv[p];
      ushort4 u = *(const ushort4*)(xw + (size_t)p * H + c4);
      a0 += bf2f(u.x) * dp; a1 += bf2f(u.y) * dp;
      a2 += bf2f(u.z) * dp; a3 += bf2f(u.w) * dp;
    }
  }
  const float4 b = *(const float4*)(bias + c4);
  y[0] = b.x + di * a0; y[1] = b.y + di * a1;
  y[2] = b.z + di * a2; y[3] = b.w + di * a3;
}

// ---------------- conv layer1: write bf16(relu(y)) ----------------
template <bool CSR>
__global__ __launch_bounds__(TPB) void k_conv1(const ushort* __restrict__ xw,
    ushort* __restrict__ out, const int* __restrict__ parent,
    const int* __restrict__ offs, const int* __restrict__ childs,
    const float* __restrict__ dinv, const float* __restrict__ bias, int N, int H) {
  int node = (blockIdx.x * TPB + threadIdx.x) >> 6;
  if (node >= N) return;
  int lane = threadIdx.x & 63;
  float y[4];
  conv_row<CSR>(node, lane, xw, parent, offs, childs, dinv, bias, H, y);
  ushort4 o;
  o.x = f2bf(fmaxf(y[0], 0.f)); o.y = f2bf(fmaxf(y[1], 0.f));
  o.z = f2bf(fmaxf(y[2], 0.f)); o.w = f2bf(fmaxf(y[3], 0.f));
  *(ushort4*)(out + (size_t)node * H + lane * 4) = o;
}

// ---------------- conv layer2 + pool: pool[g] += relu(y) ----------------
template <bool CSR>
__global__ __launch_bounds__(1024) void k_conv2(const ushort* __restrict__ xw,
    float* __restrict__ pool, const int* __restrict__ parent,
    const int* __restrict__ offs, const int* __restrict__ childs,
    const float* __restrict__ dinv, const float* __restrict__ bias,
    const int* __restrict__ batch, int N, int H) {
  __shared__ float s[16][256];
  __shared__ int g0s, bad;
  int w = threadIdx.x >> 6;            // wave in block: 0..15
  int lane = threadIdx.x & 63;
  int node = blockIdx.x * 16 + w;
  bool valid = node < N;
  int nd = valid ? node : (blockIdx.x * 16);  // clamp for loads
  int g = batch[nd];
  if (threadIdx.x == 0) { g0s = g; bad = 0; }
  __syncthreads();
  if (valid && g != g0s) bad = 1;
  float y[4] = {0.f, 0.f, 0.f, 0.f};
  if (valid) {
    conv_row<CSR>(node, lane, xw, parent, offs, childs, dinv, bias, H, y);
    y[0] = fmaxf(y[0], 0.f); y[1] = fmaxf(y[1], 0.f);
    y[2] = fmaxf(y[2], 0.f); y[3] = fmaxf(y[3], 0.f);
    if (!valid) { y[0] = y[1] = y[2] = y[3] = 0.f; }
  }
  __syncthreads();
  if (!bad) {
    int c4 = lane * 4;
    s[w][c4 + 0] = y[0]; s[w][c4 + 1] = y[1]; s[w][c4 + 2] = y[2]; s[w][c4 + 3] = y[3];
    __syncthreads();
    if (threadIdx.x < 256) {
      float acc = 0.f;
#pragma unroll
      for (int q = 0; q < 16; ++q) acc += s[q][threadIdx.x];
      atomicAdd(&pool[(size_t)g0s * H + threadIdx.x], acc);
    }
  } else if (valid) {
    int c4 = lane * 4;
    atomicAdd(&pool[(size_t)g * H + c4 + 0], y[0]);
    atomicAdd(&pool[(size_t)g * H + c4 + 1], y[1]);
    atomicAdd(&pool[(size_t)g * H + c4 + 2], y[2]);
    atomicAdd(&pool[(size_t)g * H + c4 + 3], y[3]);
  }
}

// ---------------- head ----------------
__global__ __launch_bounds__(128) void k_head(const float* __restrict__ pool_td,
    const float* __restrict__ pool_bu, const float* __restrict__ cnt,
    const float* __restrict__ Wl, const float* __restrict__ bl,
    float* __restrict__ out, int H, int C) {
  int g = blockIdx.x;
  int t = threadIdx.x;
  float inv = 1.f / cnt[g];
  float acc[8];
  for (int c = 0; c < C; ++c) acc[c] = 0.f;
  int twoH = 2 * H;
  for (int d0 = t; d0 < twoH; d0 += 128) {
    float v = (d0 < H ? pool_td[(size_t)g * H + d0] : pool_bu[(size_t)g * H + d0 - H]) * inv;
    for (int c = 0; c < C; ++c) acc[c] += v * Wl[(size_t)d0 * C + c];
  }
  __shared__ float red[128 * 8];
  for (int c = 0; c < C; ++c) red[t * C + c] = acc[c];
  __syncthreads();
  for (int off = 64; off > 0; off >>= 1) {
    if (t < off)
      for (int c = 0; c < C; ++c) red[t * C + c] += red[(t + off) * C + c];
    __syncthreads();
  }
  if (t == 0) {
    float l[8];
    float m = -1e30f;
    for (int c = 0; c < C; ++c) { l[c] = red[c] + bl[c]; m = fmaxf(m, l[c]); }
    float ssum = 0.f;
    for (int c = 0; c < C; ++c) ssum += expf(l[c] - m);
    float ls = logf(ssum);
    for (int c = 0; c < C; ++c) out[(size_t)g * C + c] = l[c] - m - ls;
  }
}

extern "C" void kernel_launch(void* const* d_in, const int* in_sizes, int n_in,
                              void* d_out, int out_size, void* d_ws, size_t ws_size,
                              hipStream_t stream) {
  const float* x     = (const float*)d_in[0];
  const int*   ei    = (const int*)d_in[1];
  const int*   batch = (const int*)d_in[2];
  const float* W1_td = (const float*)d_in[4];
  const float* b1_td = (const float*)d_in[5];
  const float* W1_bu = (const float*)d_in[6];
  const float* b1_bu = (const float*)d_in[7];
  const float* W2_td = (const float*)d_in[8];
  const float* b2_td = (const float*)d_in[9];
  const float* W2_bu = (const float*)d_in[10];
  const float* b2_bu = (const float*)d_in[11];
  const float* Wl    = (const float*)d_in[12];
  const float* bl    = (const float*)d_in[13];
  float* out = (float*)d_out;

  const int N = in_sizes[2];
  const int H = in_sizes[5];
  const int F = in_sizes[0] / N;
  const int E = in_sizes[1] / 2;
  const int C = in_sizes[13];
  const int G = out_size / C;

  const int* srcp = ei;
  const int* dstp = ei + E;

  const size_t NH = (size_t)N * H;
  const size_t NF = (size_t)N * F;
  const size_t KH = (size_t)F * H;

  ushort* x_bf   = (ushort*)d_ws;                 // N*F
  ushort* bufA   = x_bf + NF;                     // N*H  (xw)
  ushort* bufB   = bufA + NH;                     // N*H  (conv1 out)
  ushort* Wt1_td = bufB + NH;                     // F*H each
  ushort* Wt1_bu = Wt1_td + KH;
  ushort* Wt2_td = Wt1_bu + KH;
  ushort* Wt2_bu = Wt2_td + KH;
  float* dinv_td = (float*)(Wt2_bu + KH);         // N
  float* dinv_bu = dinv_td + N;                   // N
  float* R_td    = dinv_bu + N;                   // G*H
  float* R_bu    = R_td + (size_t)G * H;
  float* pool_td = R_bu + (size_t)G * H;
  float* pool_bu = pool_td + (size_t)G * H;
  float* cnt     = pool_bu + (size_t)G * H;       // G
  int* deg_td    = (int*)(cnt + G);               // N
  int* deg_bu    = deg_td + N;                    // N
  int* parent    = deg_bu + N;                    // N
  int* offs      = parent + N;                    // N+1
  int* cursor    = offs + N + 1;                  // N
  int* childs    = cursor + N;                    // E
  int* bsum      = childs + E;                    // NB
  int* first     = bsum + 1024;                   // G
  size_t need = (size_t)((char*)(first + G) - (char*)d_ws);
  if (need > ws_size) return;

  const int nbN = (N + TPB - 1) / TPB;  // also NB for scan
  const int nbE = (E + TPB - 1) / TPB;
  const int GH = G * H;
  const int nbNF8 = (int)((NF / 8 + TPB - 1) / TPB);
  const int nbKH = (int)((KH + TPB - 1) / TPB);
  const dim3 gemmGrid((N + 127) / 128);
  const int nbConv1 = (N * 64 + TPB - 1) / TPB;
  const int nbConv2 = (N + 15) / 16;

  k_init<<<nbN, TPB, 0, stream>>>(deg_td, deg_bu, parent, pool_td, pool_bu, first, cnt, N, GH, G);
  k_stats<<<nbN, TPB, 0, stream>>>(batch, first, cnt, N, G);
  k_deg<<<nbE, TPB, 0, stream>>>(srcp, dstp, deg_td, deg_bu, parent, E);
  k_dinv<<<nbN, TPB, 0, stream>>>(deg_td, deg_bu, dinv_td, dinv_bu, N);
  // CSR for bu (children lists)
  k_scan1<<<nbN, TPB, 0, stream>>>(deg_bu, bsum, N);
  k_scan2<<<1, 1024, 0, stream>>>(bsum, nbN);
  k_scan3<<<nbN, TPB, 0, stream>>>(deg_bu, bsum, offs, cursor, N);
  k_fill<<<nbE, TPB, 0, stream>>>(srcp, dstp, cursor, childs, E);

  k_root<<<dim3(G, H / 64), 64, 0, stream>>>(x, first, W2_td, W2_bu, R_td, R_bu, F, H);
  k_prep_w<<<nbKH, TPB, 0, stream>>>(W1_td, Wt1_td, F, H);
  k_prep_w<<<nbKH, TPB, 0, stream>>>(W1_bu, Wt1_bu, F, H);
  k_prep_w<<<nbKH, TPB, 0, stream>>>(W2_td, Wt2_td, H, H);
  k_prep_w<<<nbKH, TPB, 0, stream>>>(W2_bu, Wt2_bu, H, H);
  k_cast<<<nbNF8, TPB, 0, stream>>>(x, x_bf, NF / 8);

  // ---- td chain ----
  gemm_mfma<<<gemmGrid, TPB, 0, stream>>>(x_bf, Wt1_td, bufA, nullptr, batch, N, F, H);
  k_conv1<false><<<nbConv1, TPB, 0, stream>>>(bufA, bufB, parent, offs, childs, dinv_td, b1_td, N, H);
  gemm_mfma<<<gemmGrid, TPB, 0, stream>>>(bufB, Wt2_td, bufA, R_td, batch, N, H, H);
  k_conv2<false><<<nbConv2, 1024, 0, stream>>>(bufA, pool_td, parent, offs, childs, dinv_td, b2_td, batch, N, H);

  // ---- bu chain ----
  gemm_mfma<<<gemmGrid, TPB, 0, stream>>>(x_bf, Wt1_bu, bufA, nullptr, batch, N, F, H);
  k_conv1<true><<<nbConv1, TPB, 0, stream>>>(bufA, bufB, parent, offs, childs, dinv_bu, b1_bu, N, H);
  gemm_mfma<<<gemmGrid, TPB, 0, stream>>>(bufB, Wt2_bu, bufA, R_bu, batch, N, H, H);
  k_conv2<true><<<nbConv2, 1024, 0, stream>>>(bufA, pool_bu, parent, offs, childs, dinv_bu, b2_bu, batch, N, H);

  k_head<<<G, 128, 0, stream>>>(pool_td, pool_bu, cnt, Wl, bl, out, H, C);
}

// Round 4
// 654.731 us; speedup vs baseline: 4.4389x; 1.2435x over previous
//
#include <hip/hip_runtime.h>
#include <hip/hip_bf16.h>
#include <cstdint>

#define TPB 256

typedef __attribute__((ext_vector_type(8))) short short8v;
typedef __attribute__((ext_vector_type(4))) float float4v;

__device__ inline ushort f2bf(float f) {
  union { float f; uint u; } c; c.f = f;
  uint b = c.u;
  return (ushort)((b + 0x7fffu + ((b >> 16) & 1u)) >> 16);
}
__device__ inline float bf2f(ushort u) {
  union { uint u; float f; } c; c.u = ((uint)u) << 16;
  return c.f;
}

// ---------------- init ----------------
__global__ __launch_bounds__(TPB) void k_init(int* deg_td, int* deg_bu, int* parent,
    float* pool_td, float* pool_bu, int* first, float* cnt, int N, int GH, int G) {
  int i = blockIdx.x * TPB + threadIdx.x;
  if (i < N) { deg_td[i] = 1; deg_bu[i] = 1; parent[i] = -1; }
  if (i < GH) { pool_td[i] = 0.f; pool_bu[i] = 0.f; }
  if (i < G) { first[i] = 0x7fffffff; cnt[i] = 0.f; }
}

// ---------------- stats: LDS histogram ----------------
__global__ __launch_bounds__(TPB) void k_stats(const int* __restrict__ batch,
    int* first, float* cnt, int N, int G) {
  __shared__ int h[1024];
  __shared__ int fm[1024];
  if (G <= 1024) {
    for (int t = threadIdx.x; t < G; t += TPB) { h[t] = 0; fm[t] = 0x7fffffff; }
    __syncthreads();
    int i = blockIdx.x * TPB + threadIdx.x;
    if (i < N) { int g = batch[i]; atomicAdd(&h[g], 1); atomicMin(&fm[g], i); }
    __syncthreads();
    for (int t = threadIdx.x; t < G; t += TPB) {
      if (h[t]) { atomicAdd(&cnt[t], (float)h[t]); atomicMin(&first[t], fm[t]); }
    }
  } else {
    int i = blockIdx.x * TPB + threadIdx.x;
    if (i < N) { int g = batch[i]; atomicMin(&first[g], i); atomicAdd(&cnt[g], 1.f); }
  }
}

__global__ __launch_bounds__(TPB) void k_deg(const int* __restrict__ s,
    const int* __restrict__ d, int* deg_td, int* deg_bu, int* parent, int E) {
  int e = blockIdx.x * TPB + threadIdx.x;
  if (e < E) {
    atomicAdd(&deg_td[d[e]], 1);
    atomicAdd(&deg_bu[s[e]], 1);
    parent[d[e]] = s[e];  // dst unique (tree) -> race-free
  }
}

__global__ __launch_bounds__(TPB) void k_dinv(const int* __restrict__ deg_td,
    const int* __restrict__ deg_bu, float* dinv_td, float* dinv_bu, int N) {
  int i = blockIdx.x * TPB + threadIdx.x;
  if (i < N) {
    dinv_td[i] = rsqrtf((float)deg_td[i]);
    dinv_bu[i] = rsqrtf((float)deg_bu[i]);
  }
}

// ---------------- CSR build: scan of (deg_bu - 1) ----------------
__global__ __launch_bounds__(TPB) void k_scan1(const int* __restrict__ deg,
    int* bsum, int N) {
  __shared__ int s[TPB];
  int i = blockIdx.x * TPB + threadIdx.x;
  s[threadIdx.x] = (i < N) ? deg[i] - 1 : 0;
  __syncthreads();
  for (int off = TPB / 2; off > 0; off >>= 1) {
    if (threadIdx.x < off) s[threadIdx.x] += s[threadIdx.x + off];
    __syncthreads();
  }
  if (threadIdx.x == 0) bsum[blockIdx.x] = s[0];
}

__global__ __launch_bounds__(1024) void k_scan2(int* bsum, int NB) {
  __shared__ int s[1024];
  int t = threadIdx.x;
  int own = (t < NB) ? bsum[t] : 0;
  s[t] = own;
  __syncthreads();
  for (int off = 1; off < 1024; off <<= 1) {
    int v = (t >= off) ? s[t - off] : 0;
    __syncthreads();
    s[t] += v;
    __syncthreads();
  }
  if (t < NB) bsum[t] = s[t] - own;  // exclusive
}

__global__ __launch_bounds__(TPB) void k_scan3(const int* __restrict__ deg,
    const int* __restrict__ bsum, int* offs, int* cursor, int N) {
  __shared__ int s[TPB];
  int t = threadIdx.x;
  int i = blockIdx.x * TPB + t;
  int v = (i < N) ? deg[i] - 1 : 0;
  s[t] = v;
  __syncthreads();
  for (int off = 1; off < TPB; off <<= 1) {
    int u = (t >= off) ? s[t - off] : 0;
    __syncthreads();
    s[t] += u;
    __syncthreads();
  }
  int excl = bsum[blockIdx.x] + s[t] - v;
  if (i < N) {
    offs[i] = excl;
    cursor[i] = excl;
    if (i == N - 1) offs[N] = excl + v;
  }
}

__global__ __launch_bounds__(TPB) void k_fill(const int* __restrict__ s,
    const int* __restrict__ d, int* cursor, int* childs, int E) {
  int e = blockIdx.x * TPB + threadIdx.x;
  if (e < E) {
    int pos = atomicAdd(&cursor[s[e]], 1);
    childs[pos] = d[e];
  }
}

// ---------------- root projection (f32, tiny) ----------------
__global__ __launch_bounds__(64) void k_root(const float* __restrict__ x,
    const int* __restrict__ first, const float* __restrict__ W2_td,
    const float* __restrict__ W2_bu, float* R_td, float* R_bu, int F, int H) {
  __shared__ float xr[256];
  int g = blockIdx.x;
  int c = blockIdx.y * 64 + threadIdx.x;
  int root = first[g];
  for (int k = threadIdx.x; k < F; k += 64) xr[k] = fmaxf(x[(size_t)root * F + k], 0.f);
  __syncthreads();
  float atd = 0.f, abu = 0.f;
  for (int k = 0; k < F; ++k) {
    float v = xr[k];
    atd += v * W2_td[(size_t)(H + k) * H + c];
    abu += v * W2_bu[(size_t)(H + k) * H + c];
  }
  R_td[(size_t)g * H + c] = atd;
  R_bu[(size_t)g * H + c] = abu;
}

// ---------------- cast f32 -> bf16 ----------------
__global__ __launch_bounds__(TPB) void k_cast(const float* __restrict__ in,
    ushort* __restrict__ out, size_t n8) {
  size_t i = (size_t)blockIdx.x * TPB + threadIdx.x;
  if (i >= n8) return;
  const float4* p = (const float4*)in + i * 2;
  float4 v0 = p[0], v1 = p[1];
  ushort u[8];
  u[0] = f2bf(v0.x); u[1] = f2bf(v0.y); u[2] = f2bf(v0.z); u[3] = f2bf(v0.w);
  u[4] = f2bf(v1.x); u[5] = f2bf(v1.y); u[6] = f2bf(v1.z); u[7] = f2bf(v1.w);
  *(uint4*)(out + i * 8) = *(const uint4*)u;
}

// ---------------- transpose-cast weight ----------------
__global__ __launch_bounds__(TPB) void k_prep_w(const float* __restrict__ W,
    ushort* __restrict__ Wt, int K, int Nn) {
  int idx = blockIdx.x * TPB + threadIdx.x;
  if (idx >= K * Nn) return;
  int k = idx / Nn;
  int n = idx - k * Nn;
  Wt[(size_t)n * K + k] = f2bf(W[(size_t)k * Nn + n]);
}

// ---------------- bf16 MFMA GEMM: register-resident B, persistent waves ----------------
// K must be 256. 8 waves/block; wave w owns cols [w*32, w*32+32).
// B slice (8 kk x 2 strips) lives in 64 VGPRs, loaded once.
// Grid-stride over M in 32-row groups: 16 A-frag loads + 32 MFMA per iter.
__global__ __launch_bounds__(512) void gemm_mfma(
    const ushort* __restrict__ A, const ushort* __restrict__ Bt,
    ushort* __restrict__ Cbf, const float* __restrict__ Rb,
    const int* __restrict__ batch, int M, int K, int N) {
  const int wid = threadIdx.x >> 6;        // 0..7
  const int lane = threadIdx.x & 63;
  const int lr = lane & 15;
  const int lk = (lane >> 4) * 8;
  // hoist B: 2 col-strips (t = wid*2+j) x 8 k-chunks
  short8v bfr[8][2];
#pragma unroll
  for (int kk = 0; kk < 8; ++kk)
#pragma unroll
    for (int j = 0; j < 2; ++j) {
      int t = wid * 2 + j;
      bfr[kk][j] = *(const short8v*)&Bt[(size_t)(t * 16 + lr) * K + kk * 32 + lk];
    }
  const int niter = M >> 5;  // 32-row groups
  for (int it = blockIdx.x; it < niter; it += gridDim.x) {
    const int m0 = it << 5;
    const ushort* ap0 = &A[(size_t)(m0 + lr) * K + lk];
    const ushort* ap1 = &A[(size_t)(m0 + 16 + lr) * K + lk];
    short8v a0[8], a1[8];
#pragma unroll
    for (int kk = 0; kk < 8; ++kk) {
      a0[kk] = *(const short8v*)&ap0[kk * 32];
      a1[kk] = *(const short8v*)&ap1[kk * 32];
    }
    float4v acc[2][2];
    acc[0][0] = (float4v)0.f; acc[0][1] = (float4v)0.f;
    acc[1][0] = (float4v)0.f; acc[1][1] = (float4v)0.f;
#pragma unroll
    for (int kk = 0; kk < 8; ++kk) {
      acc[0][0] = __builtin_amdgcn_mfma_f32_16x16x32_bf16(a0[kk], bfr[kk][0], acc[0][0], 0, 0, 0);
      acc[0][1] = __builtin_amdgcn_mfma_f32_16x16x32_bf16(a0[kk], bfr[kk][1], acc[0][1], 0, 0, 0);
      acc[1][0] = __builtin_amdgcn_mfma_f32_16x16x32_bf16(a1[kk], bfr[kk][0], acc[1][0], 0, 0, 0);
      acc[1][1] = __builtin_amdgcn_mfma_f32_16x16x32_bf16(a1[kk], bfr[kk][1], acc[1][1], 0, 0, 0);
    }
#pragma unroll
    for (int h = 0; h < 2; ++h) {
      const int rbase = m0 + h * 16 + (lane >> 4) * 4;
#pragma unroll
      for (int r = 0; r < 4; ++r) {
        const int row = rbase + r;
        const float* rb = Rb ? &Rb[(size_t)batch[row] * N] : (const float*)nullptr;
#pragma unroll
        for (int j = 0; j < 2; ++j) {
          const int col = (wid * 2 + j) * 16 + lr;
          float v = acc[h][j][r];
          if (rb) v += rb[col];
          Cbf[(size_t)row * N + col] = f2bf(v);
        }
      }
    }
  }
}

// ---------------- conv gather core ----------------
template <bool CSR>
__device__ inline void conv_row(int node, int lane, const ushort* __restrict__ xw,
    const int* __restrict__ parent, const int* __restrict__ offs,
    const int* __restrict__ childs, const float* __restrict__ dinv,
    const float* __restrict__ bias, int H, float y[4]) {
  const int c4 = lane * 4;
  float di = dinv[node];
  ushort4 v = *(const ushort4*)(xw + (size_t)node * H + c4);
  float a0 = bf2f(v.x) * di, a1 = bf2f(v.y) * di, a2 = bf2f(v.z) * di, a3 = bf2f(v.w) * di;
  if (CSR) {
    int k0 = offs[node], k1 = offs[node + 1];
    for (int k = k0; k < k1; ++k) {
      int c = childs[k];
      float dc = dinv[c];
      ushort4 u = *(const ushort4*)(xw + (size_t)c * H + c4);
      a0 += bf2f(u.x) * dc; a1 += bf2f(u.y) * dc;
      a2 += bf2f(u.z) * dc; a3 += bf2f(u.w) * dc;
    }
  } else {
    int p = parent[node];
    if (p >= 0) {
      float dp = dinv[p];
      ushort4 u = *(const ushort4*)(xw + (size_t)p * H + c4);
      a0 += bf2f(u.x) * dp; a1 += bf2f(u.y) * dp;
      a2 += bf2f(u.z) * dp; a3 += bf2f(u.w) * dp;
    }
  }
  const float4 b = *(const float4*)(bias + c4);
  y[0] = b.x + di * a0; y[1] = b.y + di * a1;
  y[2] = b.z + di * a2; y[3] = b.w + di * a3;
}

// ---------------- conv layer1: write bf16(relu(y)) ----------------
template <bool CSR>
__global__ __launch_bounds__(TPB) void k_conv1(const ushort* __restrict__ xw,
    ushort* __restrict__ out, const int* __restrict__ parent,
    const int* __restrict__ offs, const int* __restrict__ childs,
    const float* __restrict__ dinv, const float* __restrict__ bias, int N, int H) {
  int node = (blockIdx.x * TPB + threadIdx.x) >> 6;
  if (node >= N) return;
  int lane = threadIdx.x & 63;
  float y[4];
  conv_row<CSR>(node, lane, xw, parent, offs, childs, dinv, bias, H, y);
  ushort4 o;
  o.x = f2bf(fmaxf(y[0], 0.f)); o.y = f2bf(fmaxf(y[1], 0.f));
  o.z = f2bf(fmaxf(y[2], 0.f)); o.w = f2bf(fmaxf(y[3], 0.f));
  *(ushort4*)(out + (size_t)node * H + lane * 4) = o;
}

// ---------------- conv layer2 + pool ----------------
template <bool CSR>
__global__ __launch_bounds__(1024) void k_conv2(const ushort* __restrict__ xw,
    float* __restrict__ pool, const int* __restrict__ parent,
    const int* __restrict__ offs, const int* __restrict__ childs,
    const float* __restrict__ dinv, const float* __restrict__ bias,
    const int* __restrict__ batch, int N, int H) {
  __shared__ float s[16][256];
  __shared__ int g0s, bad;
  int w = threadIdx.x >> 6;
  int lane = threadIdx.x & 63;
  int node = blockIdx.x * 16 + w;
  bool valid = node < N;
  int nd = valid ? node : (blockIdx.x * 16);
  int g = batch[nd];
  if (threadIdx.x == 0) { g0s = g; bad = 0; }
  __syncthreads();
  if (valid && g != g0s) bad = 1;
  float y[4] = {0.f, 0.f, 0.f, 0.f};
  if (valid) {
    conv_row<CSR>(node, lane, xw, parent, offs, childs, dinv, bias, H, y);
    y[0] = fmaxf(y[0], 0.f); y[1] = fmaxf(y[1], 0.f);
    y[2] = fmaxf(y[2], 0.f); y[3] = fmaxf(y[3], 0.f);
  }
  __syncthreads();
  if (!bad) {
    int c4 = lane * 4;
    s[w][c4 + 0] = y[0]; s[w][c4 + 1] = y[1]; s[w][c4 + 2] = y[2]; s[w][c4 + 3] = y[3];
    __syncthreads();
    if (threadIdx.x < 256) {
      float acc = 0.f;
#pragma unroll
      for (int q = 0; q < 16; ++q) acc += s[q][threadIdx.x];
      atomicAdd(&pool[(size_t)g0s * H + threadIdx.x], acc);
    }
  } else if (valid) {
    int c4 = lane * 4;
    atomicAdd(&pool[(size_t)g * H + c4 + 0], y[0]);
    atomicAdd(&pool[(size_t)g * H + c4 + 1], y[1]);
    atomicAdd(&pool[(size_t)g * H + c4 + 2], y[2]);
    atomicAdd(&pool[(size_t)g * H + c4 + 3], y[3]);
  }
}

// ---------------- head ----------------
__global__ __launch_bounds__(128) void k_head(const float* __restrict__ pool_td,
    const float* __restrict__ pool_bu, const float* __restrict__ cnt,
    const float* __restrict__ Wl, const float* __restrict__ bl,
    float* __restrict__ out, int H, int C) {
  int g = blockIdx.x;
  int t = threadIdx.x;
  float inv = 1.f / cnt[g];
  float acc[8];
  for (int c = 0; c < C; ++c) acc[c] = 0.f;
  int twoH = 2 * H;
  for (int d0 = t; d0 < twoH; d0 += 128) {
    float v = (d0 < H ? pool_td[(size_t)g * H + d0] : pool_bu[(size_t)g * H + d0 - H]) * inv;
    for (int c = 0; c < C; ++c) acc[c] += v * Wl[(size_t)d0 * C + c];
  }
  __shared__ float red[128 * 8];
  for (int c = 0; c < C; ++c) red[t * C + c] = acc[c];
  __syncthreads();
  for (int off = 64; off > 0; off >>= 1) {
    if (t < off)
      for (int c = 0; c < C; ++c) red[t * C + c] += red[(t + off) * C + c];
    __syncthreads();
  }
  if (t == 0) {
    float l[8];
    float m = -1e30f;
    for (int c = 0; c < C; ++c) { l[c] = red[c] + bl[c]; m = fmaxf(m, l[c]); }
    float ssum = 0.f;
    for (int c = 0; c < C; ++c) ssum += expf(l[c] - m);
    float ls = logf(ssum);
    for (int c = 0; c < C; ++c) out[(size_t)g * C + c] = l[c] - m - ls;
  }
}

extern "C" void kernel_launch(void* const* d_in, const int* in_sizes, int n_in,
                              void* d_out, int out_size, void* d_ws, size_t ws_size,
                              hipStream_t stream) {
  const float* x     = (const float*)d_in[0];
  const int*   ei    = (const int*)d_in[1];
  const int*   batch = (const int*)d_in[2];
  const float* W1_td = (const float*)d_in[4];
  const float* b1_td = (const float*)d_in[5];
  const float* W1_bu = (const float*)d_in[6];
  const float* b1_bu = (const float*)d_in[7];
  const float* W2_td = (const float*)d_in[8];
  const float* b2_td = (const float*)d_in[9];
  const float* W2_bu = (const float*)d_in[10];
  const float* b2_bu = (const float*)d_in[11];
  const float* Wl    = (const float*)d_in[12];
  const float* bl    = (const float*)d_in[13];
  float* out = (float*)d_out;

  const int N = in_sizes[2];
  const int H = in_sizes[5];
  const int F = in_sizes[0] / N;
  const int E = in_sizes[1] / 2;
  const int C = in_sizes[13];
  const int G = out_size / C;

  const int* srcp = ei;
  const int* dstp = ei + E;

  const size_t NH = (size_t)N * H;
  const size_t NF = (size_t)N * F;
  const size_t KH = (size_t)F * H;

  ushort* x_bf   = (ushort*)d_ws;                 // N*F
  ushort* bufA   = x_bf + NF;                     // N*H  (xw)
  ushort* bufB   = bufA + NH;                     // N*H  (conv1 out)
  ushort* Wt1_td = bufB + NH;                     // F*H each
  ushort* Wt1_bu = Wt1_td + KH;
  ushort* Wt2_td = Wt1_bu + KH;
  ushort* Wt2_bu = Wt2_td + KH;
  float* dinv_td = (float*)(Wt2_bu + KH);         // N
  float* dinv_bu = dinv_td + N;                   // N
  float* R_td    = dinv_bu + N;                   // G*H
  float* R_bu    = R_td + (size_t)G * H;
  float* pool_td = R_bu + (size_t)G * H;
  float* pool_bu = pool_td + (size_t)G * H;
  float* cnt     = pool_bu + (size_t)G * H;       // G
  int* deg_td    = (int*)(cnt + G);               // N
  int* deg_bu    = deg_td + N;                    // N
  int* parent    = deg_bu + N;                    // N
  int* offs      = parent + N;                    // N+1
  int* cursor    = offs + N + 1;                  // N
  int* childs    = cursor + N;                    // E
  int* bsum      = childs + E;                    // NB
  int* first     = bsum + 1024;                   // G
  size_t need = (size_t)((char*)(first + G) - (char*)d_ws);
  if (need > ws_size) return;

  const int nbN = (N + TPB - 1) / TPB;  // also NB for scan
  const int nbE = (E + TPB - 1) / TPB;
  const int GH = G * H;
  const int nbNF8 = (int)((NF / 8 + TPB - 1) / TPB);
  const int nbKH = (int)((KH + TPB - 1) / TPB);
  const dim3 gemmGrid(512);
  const int nbConv1 = (N * 64 + TPB - 1) / TPB;
  const int nbConv2 = (N + 15) / 16;

  k_init<<<nbN, TPB, 0, stream>>>(deg_td, deg_bu, parent, pool_td, pool_bu, first, cnt, N, GH, G);
  k_stats<<<nbN, TPB, 0, stream>>>(batch, first, cnt, N, G);
  k_deg<<<nbE, TPB, 0, stream>>>(srcp, dstp, deg_td, deg_bu, parent, E);
  k_dinv<<<nbN, TPB, 0, stream>>>(deg_td, deg_bu, dinv_td, dinv_bu, N);
  // CSR for bu (children lists)
  k_scan1<<<nbN, TPB, 0, stream>>>(deg_bu, bsum, N);
  k_scan2<<<1, 1024, 0, stream>>>(bsum, nbN);
  k_scan3<<<nbN, TPB, 0, stream>>>(deg_bu, bsum, offs, cursor, N);
  k_fill<<<nbE, TPB, 0, stream>>>(srcp, dstp, cursor, childs, E);

  k_root<<<dim3(G, H / 64), 64, 0, stream>>>(x, first, W2_td, W2_bu, R_td, R_bu, F, H);
  k_prep_w<<<nbKH, TPB, 0, stream>>>(W1_td, Wt1_td, F, H);
  k_prep_w<<<nbKH, TPB, 0, stream>>>(W1_bu, Wt1_bu, F, H);
  k_prep_w<<<nbKH, TPB, 0, stream>>>(W2_td, Wt2_td, H, H);
  k_prep_w<<<nbKH, TPB, 0, stream>>>(W2_bu, Wt2_bu, H, H);
  k_cast<<<nbNF8, TPB, 0, stream>>>(x, x_bf, NF / 8);

  // ---- td chain ----
  gemm_mfma<<<gemmGrid, 512, 0, stream>>>(x_bf, Wt1_td, bufA, nullptr, batch, N, F, H);
  k_conv1<false><<<nbConv1, TPB, 0, stream>>>(bufA, bufB, parent, offs, childs, dinv_td, b1_td, N, H);
  gemm_mfma<<<gemmGrid, 512, 0, stream>>>(bufB, Wt2_td, bufA, R_td, batch, N, H, H);
  k_conv2<false><<<nbConv2, 1024, 0, stream>>>(bufA, pool_td, parent, offs, childs, dinv_td, b2_td, batch, N, H);

  // ---- bu chain ----
  gemm_mfma<<<gemmGrid, 512, 0, stream>>>(x_bf, Wt1_bu, bufA, nullptr, batch, N, F, H);
  k_conv1<true><<<nbConv1, TPB, 0, stream>>>(bufA, bufB, parent, offs, childs, dinv_bu, b1_bu, N, H);
  gemm_mfma<<<gemmGrid, 512, 0, stream>>>(bufB, Wt2_bu, bufA, R_bu, batch, N, H, H);
  k_conv2<true><<<nbConv2, 1024, 0, stream>>>(bufA, pool_bu, parent, offs, childs, dinv_bu, b2_bu, batch, N, H);

  k_head<<<G, 128, 0, stream>>>(pool_td, pool_bu, cnt, Wl, bl, out, H, C);
}

// Round 5
// 613.019 us; speedup vs baseline: 4.7409x; 1.0680x over previous
//
#include <hip/hip_runtime.h>
#include <hip/hip_bf16.h>
#include <cstdint>

#define TPB 256

typedef __attribute__((ext_vector_type(8))) short short8v;
typedef __attribute__((ext_vector_type(4))) float float4v;

__device__ inline ushort f2bf(float f) {
  union { float f; uint u; } c; c.f = f;
  uint b = c.u;
  return (ushort)((b + 0x7fffu + ((b >> 16) & 1u)) >> 16);
}
__device__ inline float bf2f(ushort u) {
  union { uint u; float f; } c; c.u = ((uint)u) << 16;
  return c.f;
}

// ---------------- init ----------------
__global__ __launch_bounds__(TPB) void k_init(int* deg_td, int* deg_bu, int* parent,
    float* pool_td, float* pool_bu, int* first, float* cnt, int N, int GH, int G) {
  int i = blockIdx.x * TPB + threadIdx.x;
  if (i < N) { deg_td[i] = 1; deg_bu[i] = 1; parent[i] = -1; }
  if (i < GH) { pool_td[i] = 0.f; pool_bu[i] = 0.f; }
  if (i < G) { first[i] = 0x7fffffff; cnt[i] = 0.f; }
}

// ---------------- stats: LDS histogram ----------------
__global__ __launch_bounds__(TPB) void k_stats(const int* __restrict__ batch,
    int* first, float* cnt, int N, int G) {
  __shared__ int h[1024];
  __shared__ int fm[1024];
  if (G <= 1024) {
    for (int t = threadIdx.x; t < G; t += TPB) { h[t] = 0; fm[t] = 0x7fffffff; }
    __syncthreads();
    int i = blockIdx.x * TPB + threadIdx.x;
    if (i < N) { int g = batch[i]; atomicAdd(&h[g], 1); atomicMin(&fm[g], i); }
    __syncthreads();
    for (int t = threadIdx.x; t < G; t += TPB) {
      if (h[t]) { atomicAdd(&cnt[t], (float)h[t]); atomicMin(&first[t], fm[t]); }
    }
  } else {
    int i = blockIdx.x * TPB + threadIdx.x;
    if (i < N) { int g = batch[i]; atomicMin(&first[g], i); atomicAdd(&cnt[g], 1.f); }
  }
}

__global__ __launch_bounds__(TPB) void k_deg(const int* __restrict__ s,
    const int* __restrict__ d, int* deg_td, int* deg_bu, int* parent, int E) {
  int e = blockIdx.x * TPB + threadIdx.x;
  if (e < E) {
    atomicAdd(&deg_td[d[e]], 1);
    atomicAdd(&deg_bu[s[e]], 1);
    parent[d[e]] = s[e];  // dst unique (tree) -> race-free
  }
}

__global__ __launch_bounds__(TPB) void k_dinv(const int* __restrict__ deg_td,
    const int* __restrict__ deg_bu, float* dinv_td, float* dinv_bu, int N) {
  int i = blockIdx.x * TPB + threadIdx.x;
  if (i < N) {
    dinv_td[i] = rsqrtf((float)deg_td[i]);
    dinv_bu[i] = rsqrtf((float)deg_bu[i]);
  }
}

// ---------------- CSR build: scan of (deg_bu - 1) ----------------
__global__ __launch_bounds__(TPB) void k_scan1(const int* __restrict__ deg,
    int* bsum, int N) {
  __shared__ int s[TPB];
  int i = blockIdx.x * TPB + threadIdx.x;
  s[threadIdx.x] = (i < N) ? deg[i] - 1 : 0;
  __syncthreads();
  for (int off = TPB / 2; off > 0; off >>= 1) {
    if (threadIdx.x < off) s[threadIdx.x] += s[threadIdx.x + off];
    __syncthreads();
  }
  if (threadIdx.x == 0) bsum[blockIdx.x] = s[0];
}

__global__ __launch_bounds__(1024) void k_scan2(int* bsum, int NB) {
  __shared__ int s[1024];
  int t = threadIdx.x;
  int own = (t < NB) ? bsum[t] : 0;
  s[t] = own;
  __syncthreads();
  for (int off = 1; off < 1024; off <<= 1) {
    int v = (t >= off) ? s[t - off] : 0;
    __syncthreads();
    s[t] += v;
    __syncthreads();
  }
  if (t < NB) bsum[t] = s[t] - own;  // exclusive
}

__global__ __launch_bounds__(TPB) void k_scan3(const int* __restrict__ deg,
    const int* __restrict__ bsum, int* offs, int* cursor, int N) {
  __shared__ int s[TPB];
  int t = threadIdx.x;
  int i = blockIdx.x * TPB + t;
  int v = (i < N) ? deg[i] - 1 : 0;
  s[t] = v;
  __syncthreads();
  for (int off = 1; off < TPB; off <<= 1) {
    int u = (t >= off) ? s[t - off] : 0;
    __syncthreads();
    s[t] += u;
    __syncthreads();
  }
  int excl = bsum[blockIdx.x] + s[t] - v;
  if (i < N) {
    offs[i] = excl;
    cursor[i] = excl;
    if (i == N - 1) offs[N] = excl + v;
  }
}

__global__ __launch_bounds__(TPB) void k_fill(const int* __restrict__ s,
    const int* __restrict__ d, int* cursor, int* childs, int E) {
  int e = blockIdx.x * TPB + threadIdx.x;
  if (e < E) {
    int pos = atomicAdd(&cursor[s[e]], 1);
    childs[pos] = d[e];
  }
}

// ---------------- root projection (f32, tiny) ----------------
__global__ __launch_bounds__(64) void k_root(const float* __restrict__ x,
    const int* __restrict__ first, const float* __restrict__ W2_td,
    const float* __restrict__ W2_bu, float* R_td, float* R_bu, int F, int H) {
  __shared__ float xr[256];
  int g = blockIdx.x;
  int c = blockIdx.y * 64 + threadIdx.x;
  int root = first[g];
  for (int k = threadIdx.x; k < F; k += 64) xr[k] = fmaxf(x[(size_t)root * F + k], 0.f);
  __syncthreads();
  float atd = 0.f, abu = 0.f;
  for (int k = 0; k < F; ++k) {
    float v = xr[k];
    atd += v * W2_td[(size_t)(H + k) * H + c];
    abu += v * W2_bu[(size_t)(H + k) * H + c];
  }
  R_td[(size_t)g * H + c] = atd;
  R_bu[(size_t)g * H + c] = abu;
}

// ---------------- cast f32 -> bf16 ----------------
__global__ __launch_bounds__(TPB) void k_cast(const float* __restrict__ in,
    ushort* __restrict__ out, size_t n8) {
  size_t i = (size_t)blockIdx.x * TPB + threadIdx.x;
  if (i >= n8) return;
  const float4* p = (const float4*)in + i * 2;
  float4 v0 = p[0], v1 = p[1];
  ushort u[8];
  u[0] = f2bf(v0.x); u[1] = f2bf(v0.y); u[2] = f2bf(v0.z); u[3] = f2bf(v0.w);
  u[4] = f2bf(v1.x); u[5] = f2bf(v1.y); u[6] = f2bf(v1.z); u[7] = f2bf(v1.w);
  *(uint4*)(out + i * 8) = *(const uint4*)u;
}

// ---------------- transpose-cast weight ----------------
__global__ __launch_bounds__(TPB) void k_prep_w(const float* __restrict__ W,
    ushort* __restrict__ Wt, int K, int Nn) {
  int idx = blockIdx.x * TPB + threadIdx.x;
  if (idx >= K * Nn) return;
  int k = idx / Nn;
  int n = idx - k * Nn;
  Wt[(size_t)n * K + k] = f2bf(W[(size_t)k * Nn + n]);
}

// ---------------- bf16 MFMA GEMM: register-resident B (32 rows x 64 cols per wave) ----------------
// K must be 256. 4 waves/block; wave w owns cols [w*64, w*64+64) as 4 strips of 16.
// B slice = 8 kk x 4 strips = 128 VGPR, loaded ONCE (launch_bounds min-waves=1 so
// the register allocator has no occupancy pressure to sink the loads back into
// the loop — R4's VGPR_Count=56 proved it did exactly that at (512,default)).
__global__ __launch_bounds__(256, 1) void gemm_mfma(
    const ushort* __restrict__ A, const ushort* __restrict__ Bt,
    ushort* __restrict__ Cbf, const float* __restrict__ Rb,
    const int* __restrict__ batch, int M, int K, int N) {
  const int wid = threadIdx.x >> 6;        // 0..3
  const int lane = threadIdx.x & 63;
  const int lr = lane & 15;
  const int lk = (lane >> 4) * 8;
  short8v bfr[8][4];
#pragma unroll
  for (int kk = 0; kk < 8; ++kk)
#pragma unroll
    for (int j = 0; j < 4; ++j) {
      int t = wid * 4 + j;
      bfr[kk][j] = *(const short8v*)&Bt[(size_t)(t * 16 + lr) * K + kk * 32 + lk];
    }
  const int niter = M >> 5;  // 32-row groups
  for (int it = blockIdx.x; it < niter; it += gridDim.x) {
    const int m0 = it << 5;
    const ushort* ap0 = &A[(size_t)(m0 + lr) * K + lk];
    const ushort* ap1 = &A[(size_t)(m0 + 16 + lr) * K + lk];
    short8v a0[8], a1[8];
#pragma unroll
    for (int kk = 0; kk < 8; ++kk) {
      a0[kk] = *(const short8v*)&ap0[kk * 32];
      a1[kk] = *(const short8v*)&ap1[kk * 32];
    }
    float4v acc[2][4];
#pragma unroll
    for (int h = 0; h < 2; ++h)
#pragma unroll
      for (int j = 0; j < 4; ++j) acc[h][j] = (float4v)0.f;
#pragma unroll
    for (int kk = 0; kk < 8; ++kk) {
#pragma unroll
      for (int j = 0; j < 4; ++j) {
        acc[0][j] = __builtin_amdgcn_mfma_f32_16x16x32_bf16(a0[kk], bfr[kk][j], acc[0][j], 0, 0, 0);
        acc[1][j] = __builtin_amdgcn_mfma_f32_16x16x32_bf16(a1[kk], bfr[kk][j], acc[1][j], 0, 0, 0);
      }
    }
#pragma unroll
    for (int h = 0; h < 2; ++h) {
      const int rbase = m0 + h * 16 + (lane >> 4) * 4;
#pragma unroll
      for (int r = 0; r < 4; ++r) {
        const int row = rbase + r;
        const float* rb = Rb ? &Rb[(size_t)batch[row] * N] : (const float*)nullptr;
#pragma unroll
        for (int j = 0; j < 4; ++j) {
          const int col = (wid * 4 + j) * 16 + lr;
          float v = acc[h][j][r];
          if (rb) v += rb[col];
          Cbf[(size_t)row * N + col] = f2bf(v);
        }
      }
    }
  }
}

// ---------------- conv gather core ----------------
template <bool CSR>
__device__ inline void conv_row(int node, int lane, const ushort* __restrict__ xw,
    const int* __restrict__ parent, const int* __restrict__ offs,
    const int* __restrict__ childs, const float* __restrict__ dinv,
    const float* __restrict__ bias, int H, float y[4]) {
  const int c4 = lane * 4;
  float di = dinv[node];
  ushort4 v = *(const ushort4*)(xw + (size_t)node * H + c4);
  float a0 = bf2f(v.x) * di, a1 = bf2f(v.y) * di, a2 = bf2f(v.z) * di, a3 = bf2f(v.w) * di;
  if (CSR) {
    int k0 = offs[node], k1 = offs[node + 1];
    for (int k = k0; k < k1; ++k) {
      int c = childs[k];
      float dc = dinv[c];
      ushort4 u = *(const ushort4*)(xw + (size_t)c * H + c4);
      a0 += bf2f(u.x) * dc; a1 += bf2f(u.y) * dc;
      a2 += bf2f(u.z) * dc; a3 += bf2f(u.w) * dc;
    }
  } else {
    int p = parent[node];
    if (p >= 0) {
      float dp = dinv[p];
      ushort4 u = *(const ushort4*)(xw + (size_t)p * H + c4);
      a0 += bf2f(u.x) * dp; a1 += bf2f(u.y) * dp;
      a2 += bf2f(u.z) * dp; a3 += bf2f(u.w) * dp;
    }
  }
  const float4 b = *(const float4*)(bias + c4);
  y[0] = b.x + di * a0; y[1] = b.y + di * a1;
  y[2] = b.z + di * a2; y[3] = b.w + di * a3;
}

// ---------------- conv layer1: write bf16(relu(y)) ----------------
template <bool CSR>
__global__ __launch_bounds__(TPB) void k_conv1(const ushort* __restrict__ xw,
    ushort* __restrict__ out, const int* __restrict__ parent,
    const int* __restrict__ offs, const int* __restrict__ childs,
    const float* __restrict__ dinv, const float* __restrict__ bias, int N, int H) {
  int node = (blockIdx.x * TPB + threadIdx.x) >> 6;
  if (node >= N) return;
  int lane = threadIdx.x & 63;
  float y[4];
  conv_row<CSR>(node, lane, xw, parent, offs, childs, dinv, bias, H, y);
  ushort4 o;
  o.x = f2bf(fmaxf(y[0], 0.f)); o.y = f2bf(fmaxf(y[1], 0.f));
  o.z = f2bf(fmaxf(y[2], 0.f)); o.w = f2bf(fmaxf(y[3], 0.f));
  *(ushort4*)(out + (size_t)node * H + lane * 4) = o;
}

// ---------------- conv layer2 + pool ----------------
template <bool CSR>
__global__ __launch_bounds__(1024) void k_conv2(const ushort* __restrict__ xw,
    float* __restrict__ pool, const int* __restrict__ parent,
    const int* __restrict__ offs, const int* __restrict__ childs,
    const float* __restrict__ dinv, const float* __restrict__ bias,
    const int* __restrict__ batch, int N, int H) {
  __shared__ float s[16][256];
  __shared__ int g0s, bad;
  int w = threadIdx.x >> 6;
  int lane = threadIdx.x & 63;
  int node = blockIdx.x * 16 + w;
  bool valid = node < N;
  int nd = valid ? node : (blockIdx.x * 16);
  int g = batch[nd];
  if (threadIdx.x == 0) { g0s = g; bad = 0; }
  __syncthreads();
  if (valid && g != g0s) bad = 1;
  float y[4] = {0.f, 0.f, 0.f, 0.f};
  if (valid) {
    conv_row<CSR>(node, lane, xw, parent, offs, childs, dinv, bias, H, y);
    y[0] = fmaxf(y[0], 0.f); y[1] = fmaxf(y[1], 0.f);
    y[2] = fmaxf(y[2], 0.f); y[3] = fmaxf(y[3], 0.f);
  }
  __syncthreads();
  if (!bad) {
    int c4 = lane * 4;
    s[w][c4 + 0] = y[0]; s[w][c4 + 1] = y[1]; s[w][c4 + 2] = y[2]; s[w][c4 + 3] = y[3];
    __syncthreads();
    if (threadIdx.x < 256) {
      float acc = 0.f;
#pragma unroll
      for (int q = 0; q < 16; ++q) acc += s[q][threadIdx.x];
      atomicAdd(&pool[(size_t)g0s * H + threadIdx.x], acc);
    }
  } else if (valid) {
    int c4 = lane * 4;
    atomicAdd(&pool[(size_t)g * H + c4 + 0], y[0]);
    atomicAdd(&pool[(size_t)g * H + c4 + 1], y[1]);
    atomicAdd(&pool[(size_t)g * H + c4 + 2], y[2]);
    atomicAdd(&pool[(size_t)g * H + c4 + 3], y[3]);
  }
}

// ---------------- head ----------------
__global__ __launch_bounds__(128) void k_head(const float* __restrict__ pool_td,
    const float* __restrict__ pool_bu, const float* __restrict__ cnt,
    const float* __restrict__ Wl, const float* __restrict__ bl,
    float* __restrict__ out, int H, int C) {
  int g = blockIdx.x;
  int t = threadIdx.x;
  float inv = 1.f / cnt[g];
  float acc[8];
  for (int c = 0; c < C; ++c) acc[c] = 0.f;
  int twoH = 2 * H;
  for (int d0 = t; d0 < twoH; d0 += 128) {
    float v = (d0 < H ? pool_td[(size_t)g * H + d0] : pool_bu[(size_t)g * H + d0 - H]) * inv;
    for (int c = 0; c < C; ++c) acc[c] += v * Wl[(size_t)d0 * C + c];
  }
  __shared__ float red[128 * 8];
  for (int c = 0; c < C; ++c) red[t * C + c] = acc[c];
  __syncthreads();
  for (int off = 64; off > 0; off >>= 1) {
    if (t < off)
      for (int c = 0; c < C; ++c) red[t * C + c] += red[(t + off) * C + c];
    __syncthreads();
  }
  if (t == 0) {
    float l[8];
    float m = -1e30f;
    for (int c = 0; c < C; ++c) { l[c] = red[c] + bl[c]; m = fmaxf(m, l[c]); }
    float ssum = 0.f;
    for (int c = 0; c < C; ++c) ssum += expf(l[c] - m);
    float ls = logf(ssum);
    for (int c = 0; c < C; ++c) out[(size_t)g * C + c] = l[c] - m - ls;
  }
}

extern "C" void kernel_launch(void* const* d_in, const int* in_sizes, int n_in,
                              void* d_out, int out_size, void* d_ws, size_t ws_size,
                              hipStream_t stream) {
  const float* x     = (const float*)d_in[0];
  const int*   ei    = (const int*)d_in[1];
  const int*   batch = (const int*)d_in[2];
  const float* W1_td = (const float*)d_in[4];
  const float* b1_td = (const float*)d_in[5];
  const float* W1_bu = (const float*)d_in[6];
  const float* b1_bu = (const float*)d_in[7];
  const float* W2_td = (const float*)d_in[8];
  const float* b2_td = (const float*)d_in[9];
  const float* W2_bu = (const float*)d_in[10];
  const float* b2_bu = (const float*)d_in[11];
  const float* Wl    = (const float*)d_in[12];
  const float* bl    = (const float*)d_in[13];
  float* out = (float*)d_out;

  const int N = in_sizes[2];
  const int H = in_sizes[5];
  const int F = in_sizes[0] / N;
  const int E = in_sizes[1] / 2;
  const int C = in_sizes[13];
  const int G = out_size / C;

  const int* srcp = ei;
  const int* dstp = ei + E;

  const size_t NH = (size_t)N * H;
  const size_t NF = (size_t)N * F;
  const size_t KH = (size_t)F * H;

  ushort* x_bf   = (ushort*)d_ws;                 // N*F
  ushort* bufA   = x_bf + NF;                     // N*H  (xw)
  ushort* bufB   = bufA + NH;                     // N*H  (conv1 out)
  ushort* Wt1_td = bufB + NH;                     // F*H each
  ushort* Wt1_bu = Wt1_td + KH;
  ushort* Wt2_td = Wt1_bu + KH;
  ushort* Wt2_bu = Wt2_td + KH;
  float* dinv_td = (float*)(Wt2_bu + KH);         // N
  float* dinv_bu = dinv_td + N;                   // N
  float* R_td    = dinv_bu + N;                   // G*H
  float* R_bu    = R_td + (size_t)G * H;
  float* pool_td = R_bu + (size_t)G * H;
  float* pool_bu = pool_td + (size_t)G * H;
  float* cnt     = pool_bu + (size_t)G * H;       // G
  int* deg_td    = (int*)(cnt + G);               // N
  int* deg_bu    = deg_td + N;                    // N
  int* parent    = deg_bu + N;                    // N
  int* offs      = parent + N;                    // N+1
  int* cursor    = offs + N + 1;                  // N
  int* childs    = cursor + N;                    // E
  int* bsum      = childs + E;                    // NB
  int* first     = bsum + 1024;                   // G
  size_t need = (size_t)((char*)(first + G) - (char*)d_ws);
  if (need > ws_size) return;

  const int nbN = (N + TPB - 1) / TPB;  // also NB for scan
  const int nbE = (E + TPB - 1) / TPB;
  const int GH = G * H;
  const int nbNF8 = (int)((NF / 8 + TPB - 1) / TPB);
  const int nbKH = (int)((KH + TPB - 1) / TPB);
  const dim3 gemmGrid(512);
  const int nbConv1 = (N * 64 + TPB - 1) / TPB;
  const int nbConv2 = (N + 15) / 16;

  k_init<<<nbN, TPB, 0, stream>>>(deg_td, deg_bu, parent, pool_td, pool_bu, first, cnt, N, GH, G);
  k_stats<<<nbN, TPB, 0, stream>>>(batch, first, cnt, N, G);
  k_deg<<<nbE, TPB, 0, stream>>>(srcp, dstp, deg_td, deg_bu, parent, E);
  k_dinv<<<nbN, TPB, 0, stream>>>(deg_td, deg_bu, dinv_td, dinv_bu, N);
  // CSR for bu (children lists)
  k_scan1<<<nbN, TPB, 0, stream>>>(deg_bu, bsum, N);
  k_scan2<<<1, 1024, 0, stream>>>(bsum, nbN);
  k_scan3<<<nbN, TPB, 0, stream>>>(deg_bu, bsum, offs, cursor, N);
  k_fill<<<nbE, TPB, 0, stream>>>(srcp, dstp, cursor, childs, E);

  k_root<<<dim3(G, H / 64), 64, 0, stream>>>(x, first, W2_td, W2_bu, R_td, R_bu, F, H);
  k_prep_w<<<nbKH, TPB, 0, stream>>>(W1_td, Wt1_td, F, H);
  k_prep_w<<<nbKH, TPB, 0, stream>>>(W1_bu, Wt1_bu, F, H);
  k_prep_w<<<nbKH, TPB, 0, stream>>>(W2_td, Wt2_td, H, H);
  k_prep_w<<<nbKH, TPB, 0, stream>>>(W2_bu, Wt2_bu, H, H);
  k_cast<<<nbNF8, TPB, 0, stream>>>(x, x_bf, NF / 8);

  // ---- td chain ----
  gemm_mfma<<<gemmGrid, TPB, 0, stream>>>(x_bf, Wt1_td, bufA, nullptr, batch, N, F, H);
  k_conv1<false><<<nbConv1, TPB, 0, stream>>>(bufA, bufB, parent, offs, childs, dinv_td, b1_td, N, H);
  gemm_mfma<<<gemmGrid, TPB, 0, stream>>>(bufB, Wt2_td, bufA, R_td, batch, N, H, H);
  k_conv2<false><<<nbConv2, 1024, 0, stream>>>(bufA, pool_td, parent, offs, childs, dinv_td, b2_td, batch, N, H);

  // ---- bu chain ----
  gemm_mfma<<<gemmGrid, TPB, 0, stream>>>(x_bf, Wt1_bu, bufA, nullptr, batch, N, F, H);
  k_conv1<true><<<nbConv1, TPB, 0, stream>>>(bufA, bufB, parent, offs, childs, dinv_bu, b1_bu, N, H);
  gemm_mfma<<<gemmGrid, TPB, 0, stream>>>(bufB, Wt2_bu, bufA, R_bu, batch, N, H, H);
  k_conv2<true><<<nbConv2, 1024, 0, stream>>>(bufA, pool_bu, parent, offs, childs, dinv_bu, b2_bu, batch, N, H);

  k_head<<<G, 128, 0, stream>>>(pool_td, pool_bu, cnt, Wl, bl, out, H, C);
}